// Round 4
// baseline (373.458 us; speedup 1.0000x reference)
//
#include <hip/hip_runtime.h>

#define D 128
#define CAP 64      // per-node CSR capacity; P(deg>64 | Poisson(16)) ~ 2e-18
#define NPB 250     // nodes per bucket
#define NBMAX 512   // padded bucket count (pow2 for scan); nb = ceil(N/NPB) = 400
#define EPB 2048    // edges per bin block (782 blocks -> ~3/CU, balanced)
#define BCAP 5120   // records per bucket capacity (lambda = 4000, 5120 > 12 sigma)
#define NSLICE 8    // feature slices = XCD count; slice = blockIdx%8 -> one XCD's L2
#define SF 16       // features per slice (32 B bf16 per node per slice)

typedef unsigned int u32x4 __attribute__((ext_vector_type(4)));

// RNE float -> bf16 bits
__device__ __forceinline__ unsigned short f2bf(float x) {
    unsigned int u = __float_as_uint(x);
    u += 0x7FFFu + ((u >> 16) & 1u);
    return (unsigned short)(u >> 16);
}
__device__ __forceinline__ float bf2f(unsigned short b) {
    return __uint_as_float(((unsigned int)b) << 16);
}
// tanh via v_exp + v_rcp: err ~1e-6, far below the 1/8191 entry quantization.
__device__ __forceinline__ float fast_tanh(float x) {
    float e = __expf(2.0f * x);
    return 1.0f - 2.0f * __builtin_amdgcn_rcpf(e + 1.0f);
}

// ---------------------------------------------------------------------------
// Kernel 1: per-node projections + h -> bf16 (slice-major transpose) + q + tails.
// One 64-lane wave per node. hbt[slice][node][16]: lane l covers features 2l,2l+1
// -> slice l>>3, within-slice offset 2*(l&7).
__global__ __launch_bounds__(256) void proj_kernel(const float* __restrict__ h,
                                                   const float* __restrict__ gw,
                                                   const float* __restrict__ dnorm,
                                                   float4* __restrict__ q,
                                                   unsigned short* __restrict__ hbt,
                                                   unsigned int* __restrict__ tails,
                                                   int n_nodes) {
    if (blockIdx.x == 0) {   // zero the 512 bucket tails (replaces memset)
        tails[threadIdx.x] = 0u;
        tails[threadIdx.x + 256] = 0u;
    }
    int node = (int)((blockIdx.x * blockDim.x + threadIdx.x) >> 6);
    int lane = threadIdx.x & 63;
    if (node >= n_nodes) return;
    const float2* hr2 = (const float2*)(h + (size_t)node * D);
    const float2* gw2 = (const float2*)gw;
    float2 hv = hr2[lane];
    float2 wa = gw2[lane];
    float2 wb = gw2[lane + 64];
    ushort2 hvb = make_ushort2(f2bf(hv.x), f2bf(hv.y));
    *(ushort2*)(hbt + ((size_t)(lane >> 3) * n_nodes + node) * SF + 2 * (lane & 7)) = hvb;
    float s1 = hv.x * wa.x + hv.y * wa.y;
    float s2 = hv.x * wb.x + hv.y * wb.y;
    #pragma unroll
    for (int off = 32; off > 0; off >>= 1) {
        s1 += __shfl_down(s1, off, 64);
        s2 += __shfl_down(s2, off, 64);
    }
    if (lane == 0) q[node] = make_float4(s1, s2, dnorm[node], 0.0f);
}

// ---------------------------------------------------------------------------
// Kernel 2a: block-level counting sort of edges into dst-buckets.
__global__ __launch_bounds__(512) void bin_kernel(const float4* __restrict__ q,
                                                  const float* __restrict__ yes_no,
                                                  const int* __restrict__ src,
                                                  const int* __restrict__ dst,
                                                  const float* __restrict__ gate_b,
                                                  const float* __restrict__ yes_w,
                                                  const float* __restrict__ no_w,
                                                  unsigned int* __restrict__ tails,
                                                  unsigned long long* __restrict__ recs,
                                                  int n_edges, int nb) {
    __shared__ unsigned long long sorted[EPB];           // 16 KB
    __shared__ unsigned int hist[NBMAX];
    __shared__ unsigned int sbuf[NBMAX];
    __shared__ unsigned int base[NBMAX];
    __shared__ unsigned int cursor[NBMAX];
    __shared__ unsigned int gbase[NBMAX];

    int tid = threadIdx.x;
    int e0 = blockIdx.x * EPB;
    int n = n_edges - e0;
    if (n > EPB) n = EPB;

    hist[tid] = 0u;
    __syncthreads();

    // P1: bucket histogram
    for (int j = tid; j < n; j += 512) {
        unsigned int d = (unsigned int)dst[e0 + j];
        atomicAdd(&hist[d / NPB], 1u);
    }
    __syncthreads();

    // P2: exclusive scan (Hillis-Steele over 512)
    sbuf[tid] = hist[tid];
    __syncthreads();
    unsigned int* pa = sbuf;
    unsigned int* pb = gbase;   // scratch until P4
    #pragma unroll
    for (int s = 1; s < NBMAX; s <<= 1) {
        unsigned int v = pa[tid] + ((tid >= s) ? pa[tid - s] : 0u);
        pb[tid] = v;
        __syncthreads();
        unsigned int* t = pa; pa = pb; pb = t;
    }
    unsigned int ex = (tid == 0) ? 0u : pa[tid - 1];
    base[tid] = ex;
    cursor[tid] = ex;
    __syncthreads();

    float gb = gate_b[0];
    float yw = yes_w[0];
    float nw = no_w[0];

    // P3: compute entry, place into LDS at sorted position
    for (int j = tid; j < n; j += 512) {
        int e = e0 + j;
        int dd = dst[e];
        int ss = src[e];
        float yn = yes_no[e];
        float4 qt = q[dd];
        float4 qs = q[ss];
        float g = fast_tanh(qt.x + qs.y + gb);
        float y = fast_tanh(yn * yw + (1.0f - yn) * nw);
        float ce = (g + y) * 0.5f * qt.z * qs.z;       // |ce| < 1 strictly
        int qv = (int)rintf(ce * 8191.0f) + 8192;      // [1, 16383]
        unsigned int w0 = ((unsigned int)ss << 15) | (unsigned int)qv;
        unsigned int bk = (unsigned int)dd / NPB;
        unsigned int pos = atomicAdd(&cursor[bk], 1u);
        sorted[pos] = ((unsigned long long)(unsigned int)dd << 32) | (unsigned long long)w0;
    }
    __syncthreads();

    // P4: reserve global tail space per bucket
    gbase[tid] = (hist[tid] > 0u) ? atomicAdd(&tails[tid], hist[tid]) : 0u;
    __syncthreads();

    // P5: copy out, bucket runs contiguous in global
    for (int j = tid; j < n; j += 512) {
        unsigned long long r = sorted[j];
        unsigned int bk = (unsigned int)(r >> 32) / NPB;
        unsigned int gpos = gbase[bk] + ((unsigned int)j - base[bk]);
        if (gpos < BCAP)
            __builtin_nontemporal_store(r, recs + (size_t)bk * BCAP + gpos);
    }
}

// ---------------------------------------------------------------------------
// Kernel 2b: per-bucket counting sort -> CSR rows + cnt. One block per bucket.
__global__ __launch_bounds__(256) void scatter_kernel(const unsigned int* __restrict__ tails,
                                                      const unsigned long long* __restrict__ recs,
                                                      int* __restrict__ cnt,
                                                      unsigned int* __restrict__ csr,
                                                      int n_nodes) {
    __shared__ unsigned int sw0[BCAP];        // 20 KB entries in node-sorted order
    __shared__ unsigned char snl[BCAP];       // 5 KB local node id per slot
    __shared__ unsigned int hist2[256];
    __shared__ unsigned int sa[256];
    __shared__ unsigned int sb[256];
    __shared__ unsigned int rowbase[256];
    __shared__ unsigned int cursor2[256];

    int b = blockIdx.x;
    int tid = threadIdx.x;
    unsigned int nrec = tails[b];
    if (nrec > BCAP) nrec = BCAP;
    const unsigned long long* rb = recs + (size_t)b * BCAP;
    int node0 = b * NPB;

    hist2[tid] = 0u;
    __syncthreads();

    // P1: per-node histogram
    for (unsigned int j = tid; j < nrec; j += 256) {
        unsigned long long r = __builtin_nontemporal_load(rb + j);
        unsigned int nl = (unsigned int)(r >> 32) - (unsigned int)node0;
        atomicAdd(&hist2[nl], 1u);
    }
    __syncthreads();

    // P2: exclusive scan over 256
    sa[tid] = hist2[tid];
    __syncthreads();
    unsigned int* pa = sa;
    unsigned int* pb = sb;
    #pragma unroll
    for (int s = 1; s < 256; s <<= 1) {
        unsigned int v = pa[tid] + ((tid >= s) ? pa[tid - s] : 0u);
        pb[tid] = v;
        __syncthreads();
        unsigned int* t = pa; pa = pb; pb = t;
    }
    unsigned int ex = (tid == 0) ? 0u : pa[tid - 1];
    rowbase[tid] = ex;
    cursor2[tid] = ex;
    __syncthreads();

    // P3: place into node-sorted LDS order
    for (unsigned int j = tid; j < nrec; j += 256) {
        unsigned long long r = rb[j];
        unsigned int nl = (unsigned int)(r >> 32) - (unsigned int)node0;
        unsigned int pos = atomicAdd(&cursor2[nl], 1u);
        sw0[pos] = (unsigned int)r;
        snl[pos] = (unsigned char)nl;
    }
    __syncthreads();

    // P4: write CSR rows — contiguous 64B-aligned runs per node
    for (unsigned int j = tid; j < nrec; j += 256) {
        unsigned int nl = snl[j];
        unsigned int k = j - rowbase[nl];
        if (k < CAP)
            csr[(size_t)(node0 + (int)nl) * CAP + k] = sw0[j];
    }
    // P5: per-node counts (gather clamps to CAP)
    if (tid < NPB && node0 + tid < n_nodes)
        cnt[node0 + tid] = (int)hist2[tid];
}

// ---------------------------------------------------------------------------
// Kernel 3: XCD-sliced gather-accumulate.
// slice = blockIdx%8 -> under round-robin dispatch, one XCD owns one 3.2 MB
// hbt slice (fits 4 MB L2) -> the 410 MB of random row gathers become L2 hits.
// 4 lanes per node (8 B ushort4 each = 32 B slice row); csr/cnt via NT loads
// (evict-first: don't displace the resident slice).
__global__ __launch_bounds__(256) void gather_kernel(const unsigned short* __restrict__ hbt,
                                                     const int* __restrict__ cnt,
                                                     const unsigned int* __restrict__ csr,
                                                     float* __restrict__ z,
                                                     int n_nodes) {
    int slice = (int)(blockIdx.x & (NSLICE - 1));
    int node  = (int)((blockIdx.x >> 3) * 64 + (threadIdx.x >> 2));
    int ql    = (int)(threadIdx.x & 3);
    if (node >= n_nodes) return;
    int n = __builtin_nontemporal_load(cnt + node);
    if (n > CAP) n = CAP;
    const unsigned int* row = csr + (size_t)node * CAP;
    const unsigned short* hs = hbt + (size_t)slice * n_nodes * SF + 4 * ql;
    float4 acc = make_float4(0.0f, 0.0f, 0.0f, 0.0f);
    const float inv = 1.0f / 8191.0f;
    int k = 0;
    for (; k + 3 < n; k += 4) {
        u32x4 e = __builtin_nontemporal_load((const u32x4*)(row + k));
        float c0 = (float)((int)(e.x & 0x7fffu) - 8192) * inv;
        float c1 = (float)((int)(e.y & 0x7fffu) - 8192) * inv;
        float c2 = (float)((int)(e.z & 0x7fffu) - 8192) * inv;
        float c3 = (float)((int)(e.w & 0x7fffu) - 8192) * inv;
        ushort4 a = *(const ushort4*)(hs + (size_t)(e.x >> 15) * SF);
        ushort4 b = *(const ushort4*)(hs + (size_t)(e.y >> 15) * SF);
        ushort4 c = *(const ushort4*)(hs + (size_t)(e.z >> 15) * SF);
        ushort4 d = *(const ushort4*)(hs + (size_t)(e.w >> 15) * SF);
        acc.x += bf2f(a.x) * c0 + bf2f(b.x) * c1 + bf2f(c.x) * c2 + bf2f(d.x) * c3;
        acc.y += bf2f(a.y) * c0 + bf2f(b.y) * c1 + bf2f(c.y) * c2 + bf2f(d.y) * c3;
        acc.z += bf2f(a.z) * c0 + bf2f(b.z) * c1 + bf2f(c.z) * c2 + bf2f(d.z) * c3;
        acc.w += bf2f(a.w) * c0 + bf2f(b.w) * c1 + bf2f(c.w) * c2 + bf2f(d.w) * c3;
    }
    for (; k < n; ++k) {
        unsigned int e0 = __builtin_nontemporal_load(row + k);
        float c0 = (float)((int)(e0 & 0x7fffu) - 8192) * inv;
        ushort4 a = *(const ushort4*)(hs + (size_t)(e0 >> 15) * SF);
        acc.x += bf2f(a.x) * c0;
        acc.y += bf2f(a.y) * c0;
        acc.z += bf2f(a.z) * c0;
        acc.w += bf2f(a.w) * c0;
    }
    // z[node][slice*16 + ql*4 .. +3] — each quad writes one full 64 B chunk
    *(float4*)(z + (size_t)node * D + slice * SF + 4 * ql) = acc;
}

// ---------------------------------------------------------------------------
extern "C" void kernel_launch(void* const* d_in, const int* in_sizes, int n_in,
                              void* d_out, int out_size, void* d_ws, size_t ws_size,
                              hipStream_t stream) {
    const float* h       = (const float*)d_in[0];
    const float* dnorm   = (const float*)d_in[1];
    const float* yes_no  = (const float*)d_in[2];
    const float* gate_w  = (const float*)d_in[3];
    const float* gate_b  = (const float*)d_in[4];
    const float* yes_w   = (const float*)d_in[5];
    const float* no_w    = (const float*)d_in[6];
    const int*   src     = (const int*)d_in[7];
    const int*   dst     = (const int*)d_in[8];

    int n_nodes = in_sizes[0] / D;
    int n_edges = in_sizes[2];
    int nb = (n_nodes + NPB - 1) / NPB;   // 400 for N=100000 (<= NBMAX)

    // workspace layout (16B-aligned slices)
    char* ws = (char*)d_ws;
    size_t off = 0;
    auto take = [&](size_t bytes) {
        void* ptr = ws + off;
        off += (bytes + 15) & ~(size_t)15;
        return ptr;
    };
    float4*             q     = (float4*)take((size_t)n_nodes * sizeof(float4));
    unsigned short*     hbt   = (unsigned short*)take((size_t)n_nodes * D * sizeof(unsigned short));
    int*                cnt   = (int*)take((size_t)n_nodes * sizeof(int));
    unsigned int*       csr   = (unsigned int*)take((size_t)n_nodes * CAP * sizeof(unsigned int));
    unsigned int*       tails = (unsigned int*)take((size_t)NBMAX * sizeof(unsigned int));
    unsigned long long* recs  = (unsigned long long*)take((size_t)nb * BCAP * sizeof(unsigned long long));
    (void)ws_size;

    // 1. projections + h->bf16 slice-transpose + q + tail zeroing
    proj_kernel<<<(n_nodes + 3) / 4, 256, 0, stream>>>(h, gate_w, dnorm, q, hbt, tails, n_nodes);

    // 2a. coefficient + block counting-sort into dst-buckets
    bin_kernel<<<(n_edges + EPB - 1) / EPB, 512, 0, stream>>>(
        q, yes_no, src, dst, gate_b, yes_w, no_w, tails, recs, n_edges, nb);

    // 2b. per-bucket counting-sort -> CSR + cnt
    scatter_kernel<<<nb, 256, 0, stream>>>(tails, recs, cnt, csr, n_nodes);

    // 3. XCD-sliced gather-accumulate into z
    int nodeblocks = (n_nodes + 63) / 64;
    gather_kernel<<<nodeblocks * NSLICE, 256, 0, stream>>>(
        hbt, cnt, csr, (float*)d_out, n_nodes);
}

// Round 7
// 238.369 us; speedup vs baseline: 1.5667x; 1.5667x over previous
//
#include <hip/hip_runtime.h>

#define D 128
#define NPB 250    // nodes per bucket
#define NBMAX 512  // padded bucket count (pow2 for scan); nb = ceil(N/NPB) = 400
#define EPB 2048   // edges per bin block (782 blocks -> ~3/CU, balanced)
#define BCAP 5120  // records per bucket capacity (lambda = 4000, 5120 > 12 sigma)

typedef unsigned short u16x8 __attribute__((ext_vector_type(8)));
typedef float          f32x8 __attribute__((ext_vector_type(8)));
typedef float          f32x4 __attribute__((ext_vector_type(4)));

// RNE float -> bf16 bits
__device__ __forceinline__ unsigned short f2bf(float x) {
    unsigned int u = __float_as_uint(x);
    u += 0x7FFFu + ((u >> 16) & 1u);
    return (unsigned short)(u >> 16);
}
__device__ __forceinline__ float bf2f(unsigned short b) {
    return __uint_as_float(((unsigned int)b) << 16);
}
// tanh via v_exp + v_rcp: err ~1e-6, far below the 1/8191 entry quantization.
__device__ __forceinline__ float fast_tanh(float x) {
    float e = __expf(2.0f * x);
    return 1.0f - 2.0f * __builtin_amdgcn_rcpf(e + 1.0f);
}

// ---------------------------------------------------------------------------
// Kernel 1: per-node projections + h -> bf16 (row-major) + q + bucket tails.
// One 64-lane wave per node. q[node] = (p_dst, p_src, dnorm, 0)
__global__ __launch_bounds__(256) void proj_kernel(const float* __restrict__ h,
                                                   const float* __restrict__ gw,
                                                   const float* __restrict__ dnorm,
                                                   float4* __restrict__ q,
                                                   unsigned short* __restrict__ hb,
                                                   unsigned int* __restrict__ tails,
                                                   int n_nodes) {
    if (blockIdx.x == 0) {   // zero the 512 bucket tails (replaces memset)
        tails[threadIdx.x] = 0u;
        tails[threadIdx.x + 256] = 0u;
    }
    int node = (int)((blockIdx.x * blockDim.x + threadIdx.x) >> 6);
    int lane = threadIdx.x & 63;
    if (node >= n_nodes) return;
    const float2* hr2 = (const float2*)(h + (size_t)node * D);
    const float2* gw2 = (const float2*)gw;
    float2 hv = hr2[lane];
    float2 wa = gw2[lane];
    float2 wb = gw2[lane + 64];
    ushort2 hvb = make_ushort2(f2bf(hv.x), f2bf(hv.y));
    *(ushort2*)(hb + (size_t)node * D + 2 * lane) = hvb;
    float s1 = hv.x * wa.x + hv.y * wa.y;
    float s2 = hv.x * wb.x + hv.y * wb.y;
    #pragma unroll
    for (int off = 32; off > 0; off >>= 1) {
        s1 += __shfl_down(s1, off, 64);
        s2 += __shfl_down(s2, off, 64);
    }
    if (lane == 0) q[node] = make_float4(s1, s2, dnorm[node], 0.0f);
}

// ---------------------------------------------------------------------------
// Kernel 2: block-level counting sort of edges into dst-buckets.
// Output: recs[bucket*BCAP + t] = (dst<<32)|entry, entry = (src<<15)|q15.
__global__ __launch_bounds__(512) void bin_kernel(const float4* __restrict__ q,
                                                  const float* __restrict__ yes_no,
                                                  const int* __restrict__ src,
                                                  const int* __restrict__ dst,
                                                  const float* __restrict__ gate_b,
                                                  const float* __restrict__ yes_w,
                                                  const float* __restrict__ no_w,
                                                  unsigned int* __restrict__ tails,
                                                  unsigned long long* __restrict__ recs,
                                                  int n_edges, int nb) {
    __shared__ unsigned long long sorted[EPB];           // 16 KB
    __shared__ unsigned int hist[NBMAX];
    __shared__ unsigned int sbuf[NBMAX];
    __shared__ unsigned int base[NBMAX];
    __shared__ unsigned int cursor[NBMAX];
    __shared__ unsigned int gbase[NBMAX];

    int tid = threadIdx.x;
    int e0 = blockIdx.x * EPB;
    int n = n_edges - e0;
    if (n > EPB) n = EPB;

    hist[tid] = 0u;
    __syncthreads();

    // P1: bucket histogram
    for (int j = tid; j < n; j += 512) {
        unsigned int d = (unsigned int)dst[e0 + j];
        atomicAdd(&hist[d / NPB], 1u);
    }
    __syncthreads();

    // P2: exclusive scan (Hillis-Steele over 512)
    sbuf[tid] = hist[tid];
    __syncthreads();
    unsigned int* pa = sbuf;
    unsigned int* pb = gbase;   // scratch until P4
    #pragma unroll
    for (int s = 1; s < NBMAX; s <<= 1) {
        unsigned int v = pa[tid] + ((tid >= s) ? pa[tid - s] : 0u);
        pb[tid] = v;
        __syncthreads();
        unsigned int* t = pa; pa = pb; pb = t;
    }
    unsigned int ex = (tid == 0) ? 0u : pa[tid - 1];
    base[tid] = ex;
    cursor[tid] = ex;
    __syncthreads();

    float gb = gate_b[0];
    float yw = yes_w[0];
    float nw = no_w[0];

    // P3: compute entry, place into LDS at sorted position
    for (int j = tid; j < n; j += 512) {
        int e = e0 + j;
        int dd = dst[e];
        int ss = src[e];
        float yn = yes_no[e];
        float4 qt = q[dd];
        float4 qs = q[ss];
        float g = fast_tanh(qt.x + qs.y + gb);
        float y = fast_tanh(yn * yw + (1.0f - yn) * nw);
        float ce = (g + y) * 0.5f * qt.z * qs.z;       // |ce| < 1 strictly
        int qv = (int)rintf(ce * 8191.0f) + 8192;      // [1, 16383]
        unsigned int w0 = ((unsigned int)ss << 15) | (unsigned int)qv;
        unsigned int bk = (unsigned int)dd / NPB;
        unsigned int pos = atomicAdd(&cursor[bk], 1u);
        sorted[pos] = ((unsigned long long)(unsigned int)dd << 32) | (unsigned long long)w0;
    }
    __syncthreads();

    // P4: reserve global tail space per bucket
    gbase[tid] = (hist[tid] > 0u) ? atomicAdd(&tails[tid], hist[tid]) : 0u;
    __syncthreads();

    // P5: copy out, bucket runs contiguous in global
    for (int j = tid; j < n; j += 512) {
        unsigned long long r = sorted[j];
        unsigned int bk = (unsigned int)(r >> 32) / NPB;
        unsigned int gpos = gbase[bk] + ((unsigned int)j - base[bk]);
        if (gpos < BCAP)
            __builtin_nontemporal_store(r, recs + (size_t)bk * BCAP + gpos);
    }
}

// ---------------------------------------------------------------------------
// Kernel 3: fused sort+gather. One 512-thread block per bucket.
// Counting-sorts the bucket's records by node into LDS (replaces the csr
// materialization entirely: no csr/cnt arrays, no CAP drop), then each
// 16-lane group accumulates its nodes' rows: 8 bf16 (16 B)/lane from hb,
// z written with NT stores (don't evict the hb gather set from L2).
__global__ __launch_bounds__(512) void gscat_kernel(const unsigned int* __restrict__ tails,
                                                    const unsigned long long* __restrict__ recs,
                                                    const unsigned short* __restrict__ hb,
                                                    float* __restrict__ z,
                                                    int n_nodes) {
    __shared__ unsigned int sw0[BCAP];        // 20 KB entries in node-sorted order
    __shared__ unsigned int hist2[256];
    __shared__ unsigned int sa[256];
    __shared__ unsigned int sb[256];
    __shared__ unsigned int rowbase[256];
    __shared__ unsigned int cursor2[256];

    int b = blockIdx.x;
    int tid = threadIdx.x;
    unsigned int nrec = tails[b];
    if (nrec > BCAP) nrec = BCAP;
    const unsigned long long* rb = recs + (size_t)b * BCAP;
    int node0 = b * NPB;

    if (tid < 256) hist2[tid] = 0u;
    __syncthreads();

    // P1: per-node histogram
    for (unsigned int j = tid; j < nrec; j += 512) {
        unsigned long long r = rb[j];
        unsigned int nl = (unsigned int)(r >> 32) - (unsigned int)node0;
        atomicAdd(&hist2[nl], 1u);
    }
    __syncthreads();

    // P2: exclusive scan over 256 (threads 0..255 compute; barriers uniform)
    if (tid < 256) sa[tid] = hist2[tid];
    __syncthreads();
    unsigned int* pa = sa;
    unsigned int* pb = sb;
    #pragma unroll
    for (int s = 1; s < 256; s <<= 1) {
        if (tid < 256) {
            unsigned int v = pa[tid] + ((tid >= s) ? pa[tid - s] : 0u);
            pb[tid] = v;
        }
        __syncthreads();
        unsigned int* t = pa; pa = pb; pb = t;
    }
    if (tid < 256) {
        unsigned int ex = (tid == 0) ? 0u : pa[tid - 1];
        rowbase[tid] = ex;
        cursor2[tid] = ex;
    }
    __syncthreads();

    // P3: place entries into node-sorted LDS order (recs re-read is L2-hot)
    for (unsigned int j = tid; j < nrec; j += 512) {
        unsigned long long r = rb[j];
        unsigned int nl = (unsigned int)(r >> 32) - (unsigned int)node0;
        unsigned int pos = atomicAdd(&cursor2[nl], 1u);
        sw0[pos] = (unsigned int)r;
    }
    __syncthreads();

    // P4: gather-accumulate. 32 groups x 16 lanes; group g does nodes g, g+32, ...
    int grp  = tid >> 4;
    int lane = tid & 15;
    const unsigned short* hbl = hb + 8 * lane;
    const float inv = 1.0f / 8191.0f;
    for (int nl = grp; nl < NPB; nl += 32) {
        int node = node0 + nl;
        if (node >= n_nodes) break;
        unsigned int base2 = rowbase[nl];
        int n = (int)hist2[nl];
        f32x8 acc = (f32x8)0.0f;
        int k = 0;
        for (; k + 3 < n; k += 4) {
            unsigned int e0 = sw0[base2 + k],     e1 = sw0[base2 + k + 1];
            unsigned int e2 = sw0[base2 + k + 2], e3 = sw0[base2 + k + 3];
            float c0 = (float)((int)(e0 & 0x7fffu) - 8192) * inv;
            float c1 = (float)((int)(e1 & 0x7fffu) - 8192) * inv;
            float c2 = (float)((int)(e2 & 0x7fffu) - 8192) * inv;
            float c3 = (float)((int)(e3 & 0x7fffu) - 8192) * inv;
            u16x8 a = *(const u16x8*)(hbl + (size_t)(e0 >> 15) * D);
            u16x8 bb = *(const u16x8*)(hbl + (size_t)(e1 >> 15) * D);
            u16x8 c = *(const u16x8*)(hbl + (size_t)(e2 >> 15) * D);
            u16x8 d = *(const u16x8*)(hbl + (size_t)(e3 >> 15) * D);
            #pragma unroll
            for (int j = 0; j < 8; ++j) {
                acc[j] += bf2f(a[j]) * c0 + bf2f(bb[j]) * c1 + bf2f(c[j]) * c2 + bf2f(d[j]) * c3;
            }
        }
        for (; k < n; ++k) {
            unsigned int e0 = sw0[base2 + k];
            float c0 = (float)((int)(e0 & 0x7fffu) - 8192) * inv;
            u16x8 a = *(const u16x8*)(hbl + (size_t)(e0 >> 15) * D);
            #pragma unroll
            for (int j = 0; j < 8; ++j) acc[j] += bf2f(a[j]) * c0;
        }
        f32x4 lo = { acc[0], acc[1], acc[2], acc[3] };
        f32x4 hi = { acc[4], acc[5], acc[6], acc[7] };
        f32x4* zp = (f32x4*)(z + (size_t)node * D + 8 * lane);
        __builtin_nontemporal_store(lo, zp);
        __builtin_nontemporal_store(hi, zp + 1);
    }
}

// ---------------------------------------------------------------------------
extern "C" void kernel_launch(void* const* d_in, const int* in_sizes, int n_in,
                              void* d_out, int out_size, void* d_ws, size_t ws_size,
                              hipStream_t stream) {
    const float* h       = (const float*)d_in[0];
    const float* dnorm   = (const float*)d_in[1];
    const float* yes_no  = (const float*)d_in[2];
    const float* gate_w  = (const float*)d_in[3];
    const float* gate_b  = (const float*)d_in[4];
    const float* yes_w   = (const float*)d_in[5];
    const float* no_w    = (const float*)d_in[6];
    const int*   src     = (const int*)d_in[7];
    const int*   dst     = (const int*)d_in[8];

    int n_nodes = in_sizes[0] / D;
    int n_edges = in_sizes[2];
    int nb = (n_nodes + NPB - 1) / NPB;   // 400 for N=100000 (<= NBMAX)

    // workspace layout (16B-aligned slices)
    char* ws = (char*)d_ws;
    size_t off = 0;
    auto take = [&](size_t bytes) {
        void* ptr = ws + off;
        off += (bytes + 15) & ~(size_t)15;
        return ptr;
    };
    float4*             q     = (float4*)take((size_t)n_nodes * sizeof(float4));
    unsigned short*     hb    = (unsigned short*)take((size_t)n_nodes * D * sizeof(unsigned short));
    unsigned int*       tails = (unsigned int*)take((size_t)NBMAX * sizeof(unsigned int));
    unsigned long long* recs  = (unsigned long long*)take((size_t)nb * BCAP * sizeof(unsigned long long));
    (void)ws_size;

    // 1. projections + h->bf16 + q + tail zeroing
    proj_kernel<<<(n_nodes + 3) / 4, 256, 0, stream>>>(h, gate_w, dnorm, q, hb, tails, n_nodes);

    // 2. coefficient + block counting-sort into dst-buckets
    bin_kernel<<<(n_edges + EPB - 1) / EPB, 512, 0, stream>>>(
        q, yes_no, src, dst, gate_b, yes_w, no_w, tails, recs, n_edges, nb);

    // 3. fused per-bucket sort + gather-accumulate into z
    gscat_kernel<<<nb, 512, 0, stream>>>(tails, recs, hb, (float*)d_out, n_nodes);
}